// Round 1
// baseline (539.808 us; speedup 1.0000x reference)
//
#include <hip/hip_runtime.h>
#include <hip/hip_bf16.h>
#include <math.h>

// CMDTLoss: supervised-contrastive loss on FFT'd features.
// Plancherel: Re(FFT(u)·conj(FFT(v))) = D*(u·v), ||FFT(u)|| = sqrt(D)*||u||
// => cosine similarity of FFT'd rows == cosine similarity of raw rows.
// So: sim = (F F^T normalized)/tau, then masked log-prob reduction.

#define NROWS 4096
#define DDIM  512
#define TILE  128
#define KB    16

__global__ __launch_bounds__(64) void norm_kernel(const float* __restrict__ F,
                                                  float* __restrict__ invn) {
    int row = blockIdx.x;
    const float* p = F + (size_t)row * DDIM;
    float s = 0.f;
    for (int k = threadIdx.x; k < DDIM; k += 64) {
        float v = p[k];
        s = fmaf(v, v, s);
    }
    for (int m = 1; m < 64; m <<= 1) s += __shfl_xor(s, m, 64);
    if (threadIdx.x == 0) invn[row] = rsqrtf(s);
}

__global__ void init_kernel(float* __restrict__ S, float* __restrict__ P,
                            int* __restrict__ hist) {
    int t = blockIdx.x * blockDim.x + threadIdx.x;
    if (t < NROWS) { S[t] = 0.f; P[t] = 0.f; }
    if (t < 128) hist[t] = 0;
}

__global__ void hist_kernel(const int* __restrict__ labels, int* __restrict__ hist) {
    int t = blockIdx.x * blockDim.x + threadIdx.x;
    if (t < NROWS) atomicAdd(&hist[labels[t]], 1);
}

// Fused GEMM (F F^T) + normalize + exp/mask row reductions.
// Grid (32,32), block 256.  128x128 tile, 8x8 per thread.
__global__ __launch_bounds__(256) void fused_kernel(
    const float* __restrict__ F, const float* __restrict__ invn,
    const int* __restrict__ labels,
    float* __restrict__ S, float* __restrict__ P) {
    __shared__ float As[KB][TILE + 1];
    __shared__ float Bs[KB][TILE + 1];

    const int tid = threadIdx.x;
    const int tx = tid & 15;        // column group 0..15
    const int ty = tid >> 4;        // row group 0..15
    const int ib = blockIdx.y * TILE;
    const int jb = blockIdx.x * TILE;

    float acc[8][8];
#pragma unroll
    for (int r = 0; r < 8; ++r)
#pragma unroll
        for (int c = 0; c < 8; ++c) acc[r][c] = 0.f;

    for (int k0 = 0; k0 < DDIM; k0 += KB) {
        // 128 rows x 16 k each = 2048 floats per tile; 256 threads -> 8 each.
        // t -> (i = t/16, k = t%16): 16 consecutive threads read 16 consecutive
        // floats of one row (64B segment), conflict-free LDS writes (pad +1).
#pragma unroll
        for (int t = tid; t < TILE * KB; t += 256) {
            int i = t >> 4;
            int k = t & 15;
            As[k][i] = F[(size_t)(ib + i) * DDIM + k0 + k];
            Bs[k][i] = F[(size_t)(jb + i) * DDIM + k0 + k];
        }
        __syncthreads();
#pragma unroll
        for (int k = 0; k < KB; ++k) {
            float a[8], b[8];
#pragma unroll
            for (int r = 0; r < 8; ++r) a[r] = As[k][ty * 8 + r];
#pragma unroll
            for (int c = 0; c < 8; ++c) b[c] = Bs[k][tx * 8 + c];
#pragma unroll
            for (int r = 0; r < 8; ++r)
#pragma unroll
                for (int c = 0; c < 8; ++c)
                    acc[r][c] = fmaf(a[r], b[c], acc[r][c]);
        }
        __syncthreads();
    }

    // Epilogue: sim -> exp-sum (diag excluded) and masked sim-sum per row.
    float inA[8], inB[8];
    int lA[8], lB[8];
#pragma unroll
    for (int r = 0; r < 8; ++r) {
        int i = ib + ty * 8 + r;
        inA[r] = invn[i];
        lA[r] = labels[i];
    }
#pragma unroll
    for (int c = 0; c < 8; ++c) {
        int j = jb + tx * 8 + c;
        inB[c] = invn[j];
        lB[c] = labels[j];
    }

    float esum[8], psum[8];
#pragma unroll
    for (int r = 0; r < 8; ++r) { esum[r] = 0.f; psum[r] = 0.f; }

#pragma unroll
    for (int r = 0; r < 8; ++r) {
        int i = ib + ty * 8 + r;
#pragma unroll
        for (int c = 0; c < 8; ++c) {
            int j = jb + tx * 8 + c;
            float sim = acc[r][c] * inA[r] * inB[c] * 10.0f;  // 1/TEMPERATURE
            if (i != j) {
                esum[r] += __expf(sim);
                if (lA[r] == lB[c]) psum[r] += sim;
            }
        }
    }

    // Reduce across the 16 column threads (lane bits 0..3 within the wave).
#pragma unroll
    for (int m = 1; m < 16; m <<= 1) {
#pragma unroll
        for (int r = 0; r < 8; ++r) {
            esum[r] += __shfl_xor(esum[r], m, 64);
            psum[r] += __shfl_xor(psum[r], m, 64);
        }
    }
    if (tx == 0) {
#pragma unroll
        for (int r = 0; r < 8; ++r) {
            int i = ib + ty * 8 + r;
            atomicAdd(&S[i], esum[r]);
            atomicAdd(&P[i], psum[r]);
        }
    }
}

__global__ __launch_bounds__(256) void final_kernel(
    const float* __restrict__ S, const float* __restrict__ P,
    const int* __restrict__ labels, const int* __restrict__ hist,
    float* __restrict__ out) {
    float local = 0.f;
    for (int i = threadIdx.x; i < NROWS; i += 256) {
        float cnt = (float)(hist[labels[i]] - 1);
        float term = (P[i] - cnt * logf(S[i])) / (cnt + 1e-8f);
        local += term;
    }
    for (int m = 1; m < 64; m <<= 1) local += __shfl_xor(local, m, 64);
    __shared__ float red[4];
    int wave = threadIdx.x >> 6;
    if ((threadIdx.x & 63) == 0) red[wave] = local;
    __syncthreads();
    if (threadIdx.x == 0) {
        out[0] = -(red[0] + red[1] + red[2] + red[3]) / (float)NROWS;
    }
}

extern "C" void kernel_launch(void* const* d_in, const int* in_sizes, int n_in,
                              void* d_out, int out_size, void* d_ws, size_t ws_size,
                              hipStream_t stream) {
    const float* F = (const float*)d_in[0];
    const int* labels = (const int*)d_in[1];
    float* out = (float*)d_out;

    // Workspace layout (floats): invn[4096] | S[4096] | P[4096] | hist[128 ints]
    float* invn = (float*)d_ws;
    float* S = invn + NROWS;
    float* P = S + NROWS;
    int* hist = (int*)(P + NROWS);

    init_kernel<<<dim3((NROWS + 255) / 256), dim3(256), 0, stream>>>(S, P, hist);
    norm_kernel<<<dim3(NROWS), dim3(64), 0, stream>>>(F, invn);
    hist_kernel<<<dim3((NROWS + 255) / 256), dim3(256), 0, stream>>>(labels, hist);
    fused_kernel<<<dim3(NROWS / TILE, NROWS / TILE), dim3(256), 0, stream>>>(
        F, invn, labels, S, P);
    final_kernel<<<dim3(1), dim3(256), 0, stream>>>(S, P, labels, hist, out);
}

// Round 2
// 126.384 us; speedup vs baseline: 4.2712x; 4.2712x over previous
//
#include <hip/hip_runtime.h>
#include <hip/hip_bf16.h>
#include <math.h>

// CMDTLoss: supervised-contrastive loss on FFT'd features.
// Plancherel: Re(FFT(u)·conj(FFT(v))) = D*(u·v), ||FFT(u)|| = sqrt(D)*||u||
// => cosine sim of FFT'd rows == cosine sim of raw rows. The whole reference
// collapses to: sim = (normalized F F^T)/tau -> masked log-prob reduction.
//
// R2: bf16 MFMA GEMM (m97-style): 128x128 tile, 4 waves x 4x4 mfma 16x16x32,
// BK=32, global_load_lds width 16, fused epilogue (exp/mask/row-reduce).

#define NROWS 4096
#define DDIM  512
#define BM    128
#define BN    128
#define BK    32

typedef __attribute__((ext_vector_type(8))) short  short8;   // 8 bf16
typedef __attribute__((ext_vector_type(4))) float  floatx4;  // MFMA acc

__device__ inline unsigned short f2bf(float x) {
    // round-to-nearest-even fp32 -> bf16
    unsigned u = __float_as_uint(x);
    return (unsigned short)((u + 0x7FFFu + ((u >> 16) & 1u)) >> 16);
}

__global__ __launch_bounds__(256) void convert_kernel(
    const float* __restrict__ F, unsigned short* __restrict__ Fb) {
    int t = blockIdx.x * 256 + threadIdx.x;  // one float4 per thread
    float4 v = ((const float4*)F)[t];
    ushort4 o;
    o.x = f2bf(v.x); o.y = f2bf(v.y); o.z = f2bf(v.z); o.w = f2bf(v.w);
    ((ushort4*)Fb)[t] = o;
}

__global__ __launch_bounds__(256) void norm_kernel(const float* __restrict__ F,
                                                   float* __restrict__ invn) {
    // one wave per row, 4 rows per block
    int row = blockIdx.x * 4 + (threadIdx.x >> 6);
    int lane = threadIdx.x & 63;
    const float4* p = (const float4*)(F + (size_t)row * DDIM);
    float s = 0.f;
#pragma unroll
    for (int k = 0; k < 2; ++k) {
        float4 v = p[lane + k * 64];
        s += v.x * v.x + v.y * v.y + v.z * v.z + v.w * v.w;
    }
#pragma unroll
    for (int m = 1; m < 64; m <<= 1) s += __shfl_xor(s, m, 64);
    if (lane == 0) invn[row] = rsqrtf(s);
}

__global__ void init_kernel(float* __restrict__ S, float* __restrict__ P,
                            int* __restrict__ hist) {
    int t = blockIdx.x * blockDim.x + threadIdx.x;
    if (t < NROWS) { S[t] = 0.f; P[t] = 0.f; }
    if (t < 128) hist[t] = 0;
}

__global__ void hist_kernel(const int* __restrict__ labels, int* __restrict__ hist) {
    int t = blockIdx.x * blockDim.x + threadIdx.x;
    if (t < NROWS) atomicAdd(&hist[labels[t]], 1);
}

// Fused bf16 MFMA GEMM (F F^T) + normalize + exp/mask row reductions.
// Grid (32,32), block 256 (4 waves in 2x2; each wave a 64x64 quadrant).
__global__ __launch_bounds__(256) void fused_mfma_kernel(
    const unsigned short* __restrict__ Fb, const float* __restrict__ invn,
    const int* __restrict__ labels,
    float* __restrict__ S, float* __restrict__ P) {
    // Row-major [row][BK] bf16 tiles, NO padding (global_load_lds writes
    // wave-uniform base + lane*16 contiguously).
    __shared__ unsigned short As[BM * BK];  // 8 KB
    __shared__ unsigned short Bs[BN * BK];  // 8 KB

    const int tid = threadIdx.x;
    const int wave = tid >> 6;
    const int lane = tid & 63;
    const int wx = wave & 1;   // wave's 64-col quadrant
    const int wy = wave >> 1;  // wave's 64-row quadrant
    const int ib = blockIdx.y * BM;
    const int jb = blockIdx.x * BN;
    const int lrow = lane & 15;   // MFMA fragment row/col index
    const int lquad = lane >> 4;  // MFMA fragment k-quad

    floatx4 acc[4][4];
#pragma unroll
    for (int mi = 0; mi < 4; ++mi)
#pragma unroll
        for (int ni = 0; ni < 4; ++ni) acc[mi][ni] = (floatx4){0.f, 0.f, 0.f, 0.f};

    for (int k0 = 0; k0 < DDIM; k0 += BK) {
        __syncthreads();  // previous iter's ds_reads done before overwrite
        // Stage: 128 rows x 64 B = 512 x 16 B transfers per tile; 2/thread.
        // t -> row = t>>2, 16B-chunk q = t&3 (coalesced 64 B per row).
        int t = tid;
#pragma unroll
        for (int c = 0; c < 2; ++c, t += 256) {
            const unsigned short* ga =
                Fb + (size_t)(ib + (t >> 2)) * DDIM + k0 + (t & 3) * 8;
            const unsigned short* gb =
                Fb + (size_t)(jb + (t >> 2)) * DDIM + k0 + (t & 3) * 8;
            __builtin_amdgcn_global_load_lds(
                (const __attribute__((address_space(1))) unsigned int*)ga,
                (__attribute__((address_space(3))) unsigned int*)(As + t * 8),
                16, 0, 0);
            __builtin_amdgcn_global_load_lds(
                (const __attribute__((address_space(1))) unsigned int*)gb,
                (__attribute__((address_space(3))) unsigned int*)(Bs + t * 8),
                16, 0, 0);
        }
        __syncthreads();  // vmcnt(0) drained by compiler before barrier

        short8 a[4], b[4];
#pragma unroll
        for (int mi = 0; mi < 4; ++mi)
            a[mi] = *(const short8*)(As + (wy * 64 + mi * 16 + lrow) * BK + lquad * 8);
#pragma unroll
        for (int ni = 0; ni < 4; ++ni)
            b[ni] = *(const short8*)(Bs + (wx * 64 + ni * 16 + lrow) * BK + lquad * 8);
#pragma unroll
        for (int mi = 0; mi < 4; ++mi)
#pragma unroll
            for (int ni = 0; ni < 4; ++ni)
                acc[mi][ni] = __builtin_amdgcn_mfma_f32_16x16x32_bf16(
                    a[mi], b[ni], acc[mi][ni], 0, 0, 0);
    }

    // Epilogue. C/D layout: col = lane&15, row = lquad*4 + reg.
    float inB[4];
    int lB[4];
#pragma unroll
    for (int ni = 0; ni < 4; ++ni) {
        int j = jb + wx * 64 + ni * 16 + lrow;
        inB[ni] = invn[j];
        lB[ni] = labels[j];
    }

#pragma unroll
    for (int mi = 0; mi < 4; ++mi) {
#pragma unroll
        for (int r = 0; r < 4; ++r) {
            int i = ib + wy * 64 + mi * 16 + lquad * 4 + r;
            float inA = invn[i];
            int lA = labels[i];
            float es = 0.f, ps = 0.f;
#pragma unroll
            for (int ni = 0; ni < 4; ++ni) {
                int j = jb + wx * 64 + ni * 16 + lrow;
                float sim = acc[mi][ni][r] * inA * inB[ni] * 10.0f;  // 1/tau
                if (i != j) {
                    es += __expf(sim);
                    if (lA == lB[ni]) ps += sim;
                }
            }
            // sum across the 16 column-lanes (lane bits 0..3; quad preserved)
#pragma unroll
            for (int m = 1; m < 16; m <<= 1) {
                es += __shfl_xor(es, m, 64);
                ps += __shfl_xor(ps, m, 64);
            }
            if (lrow == 0) {
                atomicAdd(&S[i], es);
                atomicAdd(&P[i], ps);
            }
        }
    }
}

__global__ __launch_bounds__(256) void final_kernel(
    const float* __restrict__ S, const float* __restrict__ P,
    const int* __restrict__ labels, const int* __restrict__ hist,
    float* __restrict__ out) {
    float local = 0.f;
    for (int i = threadIdx.x; i < NROWS; i += 256) {
        float cnt = (float)(hist[labels[i]] - 1);
        float term = (P[i] - cnt * logf(S[i])) / (cnt + 1e-8f);
        local += term;
    }
#pragma unroll
    for (int m = 1; m < 64; m <<= 1) local += __shfl_xor(local, m, 64);
    __shared__ float red[4];
    int wave = threadIdx.x >> 6;
    if ((threadIdx.x & 63) == 0) red[wave] = local;
    __syncthreads();
    if (threadIdx.x == 0) {
        out[0] = -(red[0] + red[1] + red[2] + red[3]) / (float)NROWS;
    }
}

extern "C" void kernel_launch(void* const* d_in, const int* in_sizes, int n_in,
                              void* d_out, int out_size, void* d_ws, size_t ws_size,
                              hipStream_t stream) {
    const float* F = (const float*)d_in[0];
    const int* labels = (const int*)d_in[1];
    float* out = (float*)d_out;

    // ws layout (bytes): invn[16K] | S[16K] | P[16K] | hist[512] | Fb[4 MB]
    float* invn = (float*)d_ws;
    float* S = invn + NROWS;
    float* P = S + NROWS;
    int* hist = (int*)(P + NROWS);
    unsigned short* Fb = (unsigned short*)(hist + 128);

    init_kernel<<<dim3((NROWS + 255) / 256), dim3(256), 0, stream>>>(S, P, hist);
    convert_kernel<<<dim3(NROWS * DDIM / 4 / 256), dim3(256), 0, stream>>>(F, Fb);
    norm_kernel<<<dim3(NROWS / 4), dim3(256), 0, stream>>>(F, invn);
    hist_kernel<<<dim3((NROWS + 255) / 256), dim3(256), 0, stream>>>(labels, hist);
    fused_mfma_kernel<<<dim3(NROWS / BN, NROWS / BM), dim3(256), 0, stream>>>(
        Fb, invn, labels, S, P);
    final_kernel<<<dim3(1), dim3(256), 0, stream>>>(S, P, labels, hist, out);
}

// Round 3
// 95.459 us; speedup vs baseline: 5.6549x; 1.3240x over previous
//
#include <hip/hip_runtime.h>
#include <hip/hip_bf16.h>
#include <math.h>

// CMDTLoss: supervised-contrastive loss on FFT'd features.
// Plancherel: Re(FFT(u)·conj(FFT(v))) = D*(u·v), ||FFT(u)|| = sqrt(D)*||u||
// => cosine sim of FFT'd rows == cosine sim of raw rows. The reference
// collapses to: sim = (normalized F F^T)/tau -> masked log-prob reduction.
//
// R3: (a) exploit symmetry -- only 528 upper-tri 128x128 tiles, off-diag
// tiles feed both row- and col-sums; (b) DPP 16-lane reductions (full-rate
// VALU, no ds_swizzle); (c) fuse prep into one kernel (3 launches total);
// (d) fold sqrt(1/tau) into invn.

#define NROWS 4096
#define DDIM  512
#define BM    128
#define BN    128
#define BK    32
#define NB    32              // NROWS / BM
#define NTRI  (NB * (NB + 1) / 2)  // 528

typedef __attribute__((ext_vector_type(8))) short  short8;   // 8 bf16
typedef __attribute__((ext_vector_type(4))) float  floatx4;  // MFMA acc

__device__ inline unsigned short f2bf(float x) {
    unsigned u = __float_as_uint(x);
    return (unsigned short)((u + 0x7FFFu + ((u >> 16) & 1u)) >> 16);
}

// Butterfly sum across each 16-lane row; all lanes get the 16-lane total.
// quad_perm xor1 (0xB1), quad_perm xor2 (0x4E), row_half_mirror (0x141),
// row_mirror (0x140) -- 4 full-rate v_add_f32_dpp, no LDS pipe.
__device__ inline float dpp_add16(float v) {
    v += __int_as_float(__builtin_amdgcn_update_dpp(
        0, __float_as_int(v), 0xB1, 0xF, 0xF, true));
    v += __int_as_float(__builtin_amdgcn_update_dpp(
        0, __float_as_int(v), 0x4E, 0xF, 0xF, true));
    v += __int_as_float(__builtin_amdgcn_update_dpp(
        0, __float_as_int(v), 0x141, 0xF, 0xF, true));
    v += __int_as_float(__builtin_amdgcn_update_dpp(
        0, __float_as_int(v), 0x140, 0xF, 0xF, true));
    return v;
}

// One pass over F: convert to bf16, row sum-of-squares -> invn (with
// sqrt(1/tau) folded in), zero S/P; block 0 also builds the label histogram.
__global__ __launch_bounds__(256) void prep_kernel(
    const float* __restrict__ F, const int* __restrict__ labels,
    unsigned short* __restrict__ Fb, float* __restrict__ invn,
    float* __restrict__ S, float* __restrict__ P, int* __restrict__ hist) {
    const int wave = threadIdx.x >> 6, lane = threadIdx.x & 63;
    const int row = blockIdx.x * 4 + wave;
    const float4* p = (const float4*)(F + (size_t)row * DDIM);
    float4 v0 = p[lane];
    float4 v1 = p[lane + 64];
    float s = v0.x * v0.x + v0.y * v0.y + v0.z * v0.z + v0.w * v0.w
            + v1.x * v1.x + v1.y * v1.y + v1.z * v1.z + v1.w * v1.w;
    ushort4 o0 = { f2bf(v0.x), f2bf(v0.y), f2bf(v0.z), f2bf(v0.w) };
    ushort4 o1 = { f2bf(v1.x), f2bf(v1.y), f2bf(v1.z), f2bf(v1.w) };
    ushort4* q = (ushort4*)(Fb + (size_t)row * DDIM);
    q[lane] = o0;
    q[lane + 64] = o1;
#pragma unroll
    for (int m = 1; m < 64; m <<= 1) s += __shfl_xor(s, m, 64);
    if (lane == 0) {
        invn[row] = rsqrtf(s) * 3.16227766017f;  // * sqrt(1/TEMPERATURE)
        S[row] = 0.f;
        P[row] = 0.f;
    }
    if (blockIdx.x == 0) {
        __shared__ int h[128];
        if (threadIdx.x < 128) h[threadIdx.x] = 0;
        __syncthreads();
        for (int i = threadIdx.x; i < NROWS; i += 256)
            atomicAdd(&h[labels[i]], 1);
        __syncthreads();
        if (threadIdx.x < 128) hist[threadIdx.x] = h[threadIdx.x];
    }
}

// Symmetric fused bf16 MFMA GEMM + epilogue. Grid = NTRI blocks, 256 thr
// (4 waves, 2x2 quadrants of 64x64). Off-diag tiles: row sums for i-range,
// col sums for j-range (sim/mask symmetric). Diag tiles: row sums only
// (tile already covers both orderings), diagonal excluded per element.
__global__ __launch_bounds__(256) void fused_sym_kernel(
    const unsigned short* __restrict__ Fb, const float* __restrict__ invn,
    const int* __restrict__ labels,
    float* __restrict__ S, float* __restrict__ P) {
    __shared__ unsigned short As[BM * BK];  // 8 KB, row-major [row][BK]
    __shared__ unsigned short Bs[BN * BK];  // no padding: global_load_lds

    // linear block id -> upper-tri (bi, bj), bi <= bj
    int t = blockIdx.x;
    int bi = (int)((65.0f - sqrtf(65.0f * 65.0f - 8.0f * (float)t)) * 0.5f);
    while (bi > 0 && bi * NB - bi * (bi - 1) / 2 > t) --bi;
    while ((bi + 1) * NB - (bi + 1) * bi / 2 <= t) ++bi;
    const int bj = bi + (t - (bi * NB - bi * (bi - 1) / 2));
    const bool diag = (bi == bj);
    const int ib = bi * BM, jb = bj * BN;

    const int tid = threadIdx.x;
    const int wave = tid >> 6;
    const int lane = tid & 63;
    const int wx = wave & 1;
    const int wy = wave >> 1;
    const int lrow = lane & 15;
    const int lquad = lane >> 4;

    floatx4 acc[4][4];
#pragma unroll
    for (int mi = 0; mi < 4; ++mi)
#pragma unroll
        for (int ni = 0; ni < 4; ++ni) acc[mi][ni] = (floatx4){0.f, 0.f, 0.f, 0.f};

    for (int k0 = 0; k0 < DDIM; k0 += BK) {
        __syncthreads();
        int u = tid;
#pragma unroll
        for (int c = 0; c < 2; ++c, u += 256) {
            const unsigned short* ga =
                Fb + (size_t)(ib + (u >> 2)) * DDIM + k0 + (u & 3) * 8;
            const unsigned short* gb =
                Fb + (size_t)(jb + (u >> 2)) * DDIM + k0 + (u & 3) * 8;
            __builtin_amdgcn_global_load_lds(
                (const __attribute__((address_space(1))) unsigned int*)ga,
                (__attribute__((address_space(3))) unsigned int*)(As + u * 8),
                16, 0, 0);
            __builtin_amdgcn_global_load_lds(
                (const __attribute__((address_space(1))) unsigned int*)gb,
                (__attribute__((address_space(3))) unsigned int*)(Bs + u * 8),
                16, 0, 0);
        }
        __syncthreads();

        short8 a[4], b[4];
#pragma unroll
        for (int mi = 0; mi < 4; ++mi)
            a[mi] = *(const short8*)(As + (wy * 64 + mi * 16 + lrow) * BK + lquad * 8);
#pragma unroll
        for (int ni = 0; ni < 4; ++ni)
            b[ni] = *(const short8*)(Bs + (wx * 64 + ni * 16 + lrow) * BK + lquad * 8);
#pragma unroll
        for (int mi = 0; mi < 4; ++mi)
#pragma unroll
            for (int ni = 0; ni < 4; ++ni)
                acc[mi][ni] = __builtin_amdgcn_mfma_f32_16x16x32_bf16(
                    a[mi], b[ni], acc[mi][ni], 0, 0, 0);
    }

    // Epilogue. C/D layout: col = lrow, row = lquad*4 + reg.
    float inB[4];
    int lB[4];
#pragma unroll
    for (int ni = 0; ni < 4; ++ni) {
        int j = jb + wx * 64 + ni * 16 + lrow;
        inB[ni] = invn[j];
        lB[ni] = labels[j];
    }
    float inA[4][4];
    int lA[4][4];
#pragma unroll
    for (int mi = 0; mi < 4; ++mi)
#pragma unroll
        for (int r = 0; r < 4; ++r) {
            int i = ib + wy * 64 + mi * 16 + lquad * 4 + r;
            inA[mi][r] = invn[i];
            lA[mi][r] = labels[i];
        }

    float ecol[4] = {0.f, 0.f, 0.f, 0.f};
    float pcol[4] = {0.f, 0.f, 0.f, 0.f};

#pragma unroll
    for (int mi = 0; mi < 4; ++mi) {
#pragma unroll
        for (int r = 0; r < 4; ++r) {
            const int i = ib + wy * 64 + mi * 16 + lquad * 4 + r;
            float es = 0.f, ps = 0.f;
#pragma unroll
            for (int ni = 0; ni < 4; ++ni) {
                const int j = jb + wx * 64 + ni * 16 + lrow;
                float sim = acc[mi][ni][r] * inA[mi][r] * inB[ni];
                float e = __expf(sim);
                float pm = (lA[mi][r] == lB[ni]) ? sim : 0.f;
                if (diag && i == j) { e = 0.f; pm = 0.f; }
                es += e; ps += pm;
                ecol[ni] += e; pcol[ni] += pm;
            }
            es = dpp_add16(es);
            ps = dpp_add16(ps);
            if (lrow == 0) {
                atomicAdd(&S[i], es);
                atomicAdd(&P[i], ps);
            }
        }
    }

    if (!diag) {
        // col sums: reduce across lquad (lane bits 4,5)
#pragma unroll
        for (int ni = 0; ni < 4; ++ni) {
            float e = ecol[ni], pq = pcol[ni];
            e += __shfl_xor(e, 16, 64);
            e += __shfl_xor(e, 32, 64);
            pq += __shfl_xor(pq, 16, 64);
            pq += __shfl_xor(pq, 32, 64);
            if (lquad == 0) {
                int j = jb + wx * 64 + ni * 16 + lrow;
                atomicAdd(&S[j], e);
                atomicAdd(&P[j], pq);
            }
        }
    }
}

__global__ __launch_bounds__(1024) void final_kernel(
    const float* __restrict__ S, const float* __restrict__ P,
    const int* __restrict__ labels, const int* __restrict__ hist,
    float* __restrict__ out) {
    float local = 0.f;
    for (int i = threadIdx.x; i < NROWS; i += 1024) {
        float cnt = (float)(hist[labels[i]] - 1);
        local += (P[i] - cnt * logf(S[i])) / (cnt + 1e-8f);
    }
#pragma unroll
    for (int m = 1; m < 64; m <<= 1) local += __shfl_xor(local, m, 64);
    __shared__ float red[16];
    int wave = threadIdx.x >> 6;
    if ((threadIdx.x & 63) == 0) red[wave] = local;
    __syncthreads();
    if (threadIdx.x == 0) {
        float s = 0.f;
#pragma unroll
        for (int w = 0; w < 16; ++w) s += red[w];
        out[0] = -s / (float)NROWS;
    }
}

extern "C" void kernel_launch(void* const* d_in, const int* in_sizes, int n_in,
                              void* d_out, int out_size, void* d_ws, size_t ws_size,
                              hipStream_t stream) {
    const float* F = (const float*)d_in[0];
    const int* labels = (const int*)d_in[1];
    float* out = (float*)d_out;

    // ws layout: invn[4096 f] | S[4096 f] | P[4096 f] | hist[128 i] | Fb[4 MB]
    float* invn = (float*)d_ws;
    float* S = invn + NROWS;
    float* P = S + NROWS;
    int* hist = (int*)(P + NROWS);
    unsigned short* Fb = (unsigned short*)(hist + 128);

    prep_kernel<<<dim3(NROWS / 4), dim3(256), 0, stream>>>(
        F, labels, Fb, invn, S, P, hist);
    fused_sym_kernel<<<dim3(NTRI), dim3(256), 0, stream>>>(
        Fb, invn, labels, S, P);
    final_kernel<<<dim3(1), dim3(1024), 0, stream>>>(S, P, labels, hist, out);
}